// Round 5
// baseline (689.478 us; speedup 1.0000x reference)
//
#include <hip/hip_runtime.h>
#include <cmath>
#include <cstring>
#include <cstdlib>
#include <algorithm>

// ---------------- problem constants ----------------
#define BATCH 32

static constexpr float SC1f = 0.03872983346207417f;   // 1/sqrt(2*30*1*10^4/30^2)
static constexpr float SC2f = 0.06324555320336759f;   // 1/sqrt(250)

// table layout (float offsets inside the table blob)
#define OFF_D1W 0
#define N_D1W (10*60*19)
#define OFF_C1  (OFF_D1W + N_D1W)      // [10][20][19][19]
#define N_C1  (10*20*19*19)
#define OFF_D2W (OFF_C1 + N_C1)        // [5][20][9][9]
#define N_D2W (5*20*81)
#define OFF_DH2 (OFF_D2W + N_D2W)      // [5][9][9]
#define N_DH2 (5*81)
#define OFF_DI2 (OFF_DH2 + N_DH2)      // [5][10][9][9]
#define N_DI2 (5*10*81)
#define OFF_WO  (OFF_DI2 + N_DI2)      // [10]
#define TBL_N   (OFF_WO + 10)

__constant__ int d_RNI[9] = {9,16,21,24,25,24,21,16,9};
__constant__ int d_RS [9] = {0,9,25,46,70,95,119,140,156};

__device__ __forceinline__ float2 cmulf(float2 a, float2 b){
  return make_float2(a.x*b.x - a.y*b.y, a.x*b.y + a.y*b.x);
}

// ---------------- K_front: kf1 (block 0) | kf2 (blocks 1..79) | xf1 (blocks 80..222) ----------------
__global__ void k_front(const float* __restrict__ k1, const float* __restrict__ k2,
                        const float* __restrict__ x,
                        float2* __restrict__ kf1, float2* __restrict__ kf2,
                        float2* __restrict__ xf1){
  __shared__ float c60[60], s60[60], c20[20], s20[20];
  int t = threadIdx.x;
  if (t < 60){ float a = 6.283185307179586f * t / 60.f; c60[t]=cosf(a); s60[t]=sinf(a); }
  if (t < 20){ float a = 6.283185307179586f * t / 20.f; c20[t]=cosf(a); s20[t]=sinf(a); }
  __syncthreads();
  int bid = blockIdx.x;
  if (bid == 0){
    int o = t;
    if (o >= 100) return;
    float kv[60];
    for (int j=0;j<60;j++) kv[j] = k1[o*60+j];
    for (int mi=0; mi<19; mi++){
      int m = mi-9; float ax=0.f, ay=0.f;
      for (int j=0;j<60;j++){
        int idx = ((m*j)%60+60)%60;
        ax += kv[j]*c60[idx]; ay -= kv[j]*s60[idx];
      }
      kf1[mi*100+o] = make_float2(ax*SC1f, ay*SC1f);
    }
  } else if (bid < 80){
    int gid = (bid-1)*256 + t;
    if (gid >= 20000) return;
    int i = gid/200, o = gid%200;
    float kv[20];
    for (int p=0;p<20;p++) kv[p] = k2[(i*200+o)*20+p];
    for (int mi=0; mi<9; mi++){
      int m = mi-4; float ax=0.f, ay=0.f;
      for (int p=0;p<20;p++){
        int idx = ((m*p)%20+20)%20;
        ax += kv[p]*c20[idx]; ay -= kv[p]*s20[idx];
      }
      kf2[(size_t)(mi*100+i)*200+o] = make_float2(ax*SC2f, ay*SC2f);
    }
  } else {
    int gid = (bid-80)*256 + t;
    if (gid >= 19*32*60) return;
    int z = gid%60, b = (gid/60)%32, mi = gid/1920;
    int m = mi-9;
    const float* xr = x + (b*60 + z)*60;
    float ax=0.f, ay=0.f;
    for (int j=0;j<60;j++){
      int idx = ((m*j)%60+60)%60;
      float xv = xr[j];
      ax += xv*c60[idx]; ay -= xv*s60[idx];
    }
    xf1[(mi*32+b)*60+z] = make_float2(ax, ay);
  }
}

// ---------------- K2b: xh1[l][mi][b] ----------------
__global__ void k_xhat1(const float* __restrict__ tbl, const float2* __restrict__ xf1,
                        float2* __restrict__ xh1){
  int gid = blockIdx.x*256 + threadIdx.x;
  if (gid >= 10*19*32) return;
  int b = gid%32, mi = (gid/32)%19, l = gid/608;
  const float* d1w = tbl + OFF_D1W;
  float ax=0.f, ay=0.f;
  for (int z=0;z<60;z++){
    float w = d1w[(l*60+z)*19+mi];
    float2 v = xf1[(mi*32+b)*60+z];
    ax += w*v.x; ay += w*v.y;
  }
  xh1[(l*19+mi)*32+b] = make_float2(ax, ay);
}

// ---------------- K3: Q[b][z][mi][ni] = sum_l C1[l][z][mi][ni] * xh1[l][mi][b] ----------------
__global__ void k_Q(const float* __restrict__ tbl, const float2* __restrict__ xh1,
                    float2* __restrict__ Q){
  int gid = blockIdx.x*256 + threadIdx.x;
  if (gid >= 32*20*361) return;
  int ni = gid%19, mi = (gid/19)%19, z = (gid/361)%20, b = gid/7220;
  const float* C1 = tbl + OFF_C1;
  float ax=0.f, ay=0.f;
  for (int l=0;l<10;l++){
    float c = C1[(l*20+z)*361 + mi*19+ni];
    float2 xv = xh1[(l*19+mi)*32+b];
    ax += c*xv.x; ay += c*xv.y;
  }
  Q[gid] = make_float2(ax, ay);
}

// ---------------- K3b: P[b][z][n][j1] = sum_{mi} e^{i(mi-9)a_{j1}} Q[b][z][mi][n+9], n=0..9 ----------------
__global__ void k_P(const float2* __restrict__ Q, float2* __restrict__ P){
  __shared__ float c20[20], s20[20];
  int t = threadIdx.x;
  if (t < 20){ float a = 6.283185307179586f * t / 20.f; c20[t]=cosf(a); s20[t]=sinf(a); }
  __syncthreads();
  int gid = blockIdx.x*256 + t;
  if (gid >= 128000) return;
  int j1 = gid%20, n = (gid/20)%10, z = (gid/200)%20, b = gid/4000;
  const float2* q = Q + (size_t)(b*20+z)*361 + (n+9);
  float px=0.f, py=0.f;
  for (int mi=0;mi<19;mi++){
    int idx = (((mi-9)*j1)%20+20)%20;
    float c=c20[idx], s=s20[idx];
    float2 v = q[mi*19];
    px += c*v.x - s*v.y;
    py += c*v.y + s*v.x;
  }
  P[gid] = make_float2(px, py);
}

// ---------------- K4: fused layer-1 synthesis + ReLU + layer-2 analysis ----------------
// Per block (b,o); wave w owns z = w*5+zz. V[n][j1] in registers (lane=j1 mod 20),
// twiddles via complex recurrence; r in per-wave LDS; A per-wave LDS; slab written
// half-stored (M>=0): xf2[(b*100+o)][z][45].
// (256,3): 168-VGPR cap -> 3 blocks/CU. (256,4)=64 VGPR spilled (R2); (256,2) gave only 20% occ (R3).
__launch_bounds__(256,3)
__global__ void k_l1(const float2* __restrict__ P, const float2* __restrict__ kf1,
                     const float* __restrict__ b1, float2* __restrict__ xf2){
  int o = blockIdx.x % 100, b = blockIdx.x / 100;
  __shared__ float  rsb[4][400];   // [wave][j1][j2]
  __shared__ float2 Aw[4][100];    // [wave][j1][N 0..4]
  int t = threadIdx.x, w = t>>6, lane = t&63;
  int j1 = lane%20, jg = lane/20;  // jg==3 lanes idle in r phase
  const float a1 = 0.314159265358979f; // 2*pi/20

  // block-lifetime register constants
  float2 kc[10];
  #pragma unroll
  for (int n=0;n<10;n++){ float2 k = kf1[(n+9)*100+o]; kc[n]=make_float2(k.x,-k.y); }
  float b1v = b1[o];
  float2 w1p[4];
  #pragma unroll
  for (int k=0;k<4;k++){
    float a = a1 * (jg + 3*k);
    w1p[k] = make_float2(cosf(a), sinf(a));   // e^{+i a_{j2}}
  }
  float2 wN[2];
  #pragma unroll
  for (int pass=0;pass<2;pass++){
    int N = (lane + 64*pass)%5;
    float a = a1 * N;
    wN[pass] = make_float2(cosf(a), -sinf(a)); // e^{-i N a1}
  }
  int M = (lane<45)? lane/9 : 0;
  float2 wM = make_float2(cosf(a1*M), -sinf(a1*M)); // e^{-i M a1}

  for (int zz=0; zz<5; zz++){
    int z = w*5 + zz;
    // ---- V[n] = P[n][j1] * conj(kf1[n]) in registers ----
    float Vx[10], Vy[10];
    const float2* pz = P + (size_t)(b*20+z)*200;
    #pragma unroll
    for (int n=0;n<10;n++){
      float2 p = pz[n*20 + j1];
      Vx[n] = p.x*kc[n].x - p.y*kc[n].y;
      Vy[n] = p.x*kc[n].y + p.y*kc[n].x;
    }
    // ---- r[j1][j2] with j2/j2+10 parity pairing ----
    if (jg < 3){
      #pragma unroll
      for (int k=0;k<4;k++){
        int j2 = jg + 3*k;
        if (j2 < 10){
          float2 cur = w1p[k];
          float ae=0.f, ao=0.f;
          #pragma unroll
          for (int n=1;n<10;n++){
            float tr = Vx[n]*cur.x - Vy[n]*cur.y;
            if (n&1) ao += tr; else ae += tr;
            if (n<9) cur = cmulf(cur, w1p[k]);
          }
          float base = b1v + Vx[0];
          rsb[w][j1*20+j2]    = fmaxf(base + 2.f*(ae+ao), 0.f);
          rsb[w][j1*20+j2+10] = fmaxf(base + 2.f*(ae-ao), 0.f);
        }
      }
    }
    // wave-private LDS; a wave's DS ops complete in order -> no block barrier needed
    // ---- A[j1][N] = sum_j2 r[j1][j2] e^{-i N a_{j2}}, N=0..4 ----
    #pragma unroll
    for (int pass=0; pass<2; pass++){
      int e = lane + pass*64;
      if (e < 100){
        int aj1 = e/5;
        const float4* rrow = (const float4*)&rsb[w][aj1*20];
        float2 wNp = wN[pass];
        float2 cur = make_float2(1.f, 0.f);
        float ax=0.f, ay=0.f;
        #pragma unroll
        for (int q4=0;q4<5;q4++){
          float4 f = rrow[q4];
          ax += f.x*cur.x; ay += f.x*cur.y; cur = cmulf(cur, wNp);
          ax += f.y*cur.x; ay += f.y*cur.y; cur = cmulf(cur, wNp);
          ax += f.z*cur.x; ay += f.z*cur.y; cur = cmulf(cur, wNp);
          ax += f.w*cur.x; ay += f.w*cur.y; cur = cmulf(cur, wNp);
        }
        Aw[w][e] = make_float2(ax, ay);
      }
    }
    // ---- slab[M][Ni] = sum_j1 e^{-i M a_{j1}} A[j1][N], M=0..4, Ni=0..8 ----
    if (lane < 45){
      int Ni = lane%9, N = Ni-4;
      int sidx = (N>=0)? N : -N;
      float ysgn = (N>=0)? 1.f : -1.f;
      float2 cur = make_float2(1.f,0.f);
      float ox=0.f, oy=0.f;
      #pragma unroll
      for (int q=0;q<20;q++){
        float2 A = Aw[w][q*5+sidx];
        float Ay2 = ysgn*A.y;
        ox += cur.x*A.x - cur.y*Ay2;
        oy += cur.x*Ay2 + cur.y*A.x;
        cur = cmulf(cur, wM);
      }
      xf2[((size_t)(b*100+o)*20 + z)*45 + lane] = make_float2(ox, oy);
    }
  }
}

// ---------------- K5: xh2 from half-stored xf2 (conjugate mirror on read) ----------------
__launch_bounds__(256)
__global__ void k_xhat2(const float* __restrict__ tbl, const float2* __restrict__ xf2,
                        float2* __restrict__ xh2){
  __shared__ float2 xs[4][900]; // [ii][z][45]
  int b = blockIdx.x/25, ic = blockIdx.x%25;
  int t = threadIdx.x;
  const float2* src = xf2 + (size_t)(b*100 + ic*4)*900;
  for (int e=t;e<3600;e+=256) xs[e/900][e%900]=src[e];
  __syncthreads();
  const float* d2w = tbl + OFF_D2W;
  for (int e=t;e<1620;e+=256){
    int lmk=e>>2, ii=e&3;
    int l=lmk/81, mk=lmk%81;
    int mi=mk/9, ki=mk%9;
    int sidx; float sgn;
    if (mi>=4){ sidx=(mi-4)*9+ki; sgn=1.f; }
    else      { sidx=(4-mi)*9+(8-ki); sgn=-1.f; }
    float ax=0.f, ay=0.f;
    for (int z=0;z<20;z++){
      float wv=d2w[(l*20+z)*81+mk];
      float2 v=xs[ii][z*45+sidx];
      ax += wv*v.x; ay += wv*sgn*v.y;
    }
    xh2[(size_t)lmk*3200 + b*100 + ic*4 + ii]=make_float2(ax,ay);
  }
}

// ---------------- K6: A rows for GEMM ----------------
__global__ void k_Xp(const float* __restrict__ tbl, const float2* __restrict__ xh2,
                     float2* __restrict__ Am){
  int ni = blockIdx.y;
  int R = d_RNI[ni];
  int gid = blockIdx.x*256 + threadIdx.x;
  if (gid >= R*3200) return;
  int r = gid/3200, rem = gid%3200, b = rem/100, i = rem%100;
  int a = ni-4; if (a<0) a=-a;
  int l=a, rr=r;
  while (rr >= 2*l+1){ rr -= 2*l+1; l++; }
  int m = rr - l;
  const float* dh2 = tbl + OFF_DH2;
  float ax=0.f, ay=0.f;
  for (int ki=0; ki<2*l+1; ki++){
    int k = ki - l;
    float w = dh2[l*81 + ni*9 + (k+4)];
    float2 v = xh2[(size_t)(l*81 + (m+4)*9 + (k+4))*3200 + b*100 + i];
    ax += w*v.x; ay += w*v.y;
  }
  Am[(size_t)((d_RS[ni]+r)*32 + b)*100 + i] = make_float2(ax,ay);
}

// ---------------- K7: complex GEMM  z2[row][o] = sum_i Am[row][i] * conj(kf2[ni][i][o]) ----------------
__launch_bounds__(256)
__global__ void k_gemm(const float2* __restrict__ Am, const float2* __restrict__ kf2,
                       float2* __restrict__ z2){
  int ni = blockIdx.z;
  int rows = d_RNI[ni]*32;
  int r0 = blockIdx.x*64;
  if (r0 >= rows) return;
  int c0 = blockIdx.y*64;
  const float2* Ab = Am + (size_t)d_RS[ni]*32*100;
  const float2* Bb = kf2 + (size_t)ni*20000;
  float2* Cb = z2 + (size_t)d_RS[ni]*32*200;
  __shared__ float2 Asx[20*64];
  __shared__ float2 Bsx[20*64];
  int t = threadIdx.x;
  int tx = t%16, ty = t/16;
  float2 acc[4][4];
  for (int i2=0;i2<4;i2++) for (int j2=0;j2<4;j2++) acc[i2][j2]=make_float2(0.f,0.f);
  for (int k0=0;k0<100;k0+=20){
    for (int e=t;e<1280;e+=256){
      int m=e/20, k=e%20;
      float2 v=make_float2(0.f,0.f);
      if (r0+m<rows) v=Ab[(size_t)(r0+m)*100 + k0+k];
      Asx[k*64+m]=v;
    }
    for (int e=t;e<1280;e+=256){
      int k=e/64, n=e%64;
      float2 v=make_float2(0.f,0.f);
      if (c0+n<200){ v=Bb[(size_t)(k0+k)*200 + c0+n]; v.y=-v.y; }
      Bsx[k*64+n]=v;
    }
    __syncthreads();
    for (int k=0;k<20;k++){
      float2 av[4], bv[4];
      for (int i2=0;i2<4;i2++) av[i2]=Asx[k*64+ty*4+i2];
      for (int j2=0;j2<4;j2++) bv[j2]=Bsx[k*64+tx*4+j2];
      for (int i2=0;i2<4;i2++) for (int j2=0;j2<4;j2++){
        acc[i2][j2].x += av[i2].x*bv[j2].x - av[i2].y*bv[j2].y;
        acc[i2][j2].y += av[i2].x*bv[j2].y + av[i2].y*bv[j2].x;
      }
    }
    __syncthreads();
  }
  for (int i2=0;i2<4;i2++) for (int j2=0;j2<4;j2++){
    int row=r0+ty*4+i2, col=c0+tx*4+j2;
    if (row<rows && col<200) Cb[(size_t)row*200+col]=acc[i2][j2];
  }
}

// ---------------- K8: fused layer-2 synthesis + ReLU + quadrature pooling ----------------
// Hermitian-halved (G[-m,-n]=conj(G[m,n]), F[0] real); 2 waves, each owns 5 z,
// wave-private LDS scratch -> single block barrier.
__launch_bounds__(128)
__global__ void k_l2(const float* __restrict__ tbl, const float2* __restrict__ z2,
                     const float* __restrict__ b2, float* __restrict__ fv){
  int o = blockIdx.x % 200, b = blockIdx.x / 200;
  __shared__ float2 zlh[225];      // [l][m 0..4][nii] (m>=0 half)
  __shared__ float  c10s[10], s10s[10];
  __shared__ float2 Gw[2][45];     // [wave][m*9+nii]
  __shared__ float2 Fw[2][50];     // [wave][m*10+j2]
  __shared__ float  red2[2];
  int t = threadIdx.x, w = t>>6, lane = t&63;
  if (t < 10){ float a = 0.6283185307179586f * t; c10s[t]=cosf(a); s10s[t]=sinf(a); }
  for (int e=t;e<225;e+=128){
    int l=e/45, rm=e%45, m=rm/9, nii=rm%9;
    int n=nii-4, an = n<0?-n:n;
    float2 v=make_float2(0.f,0.f);
    if (l >= m && l >= an){
      int row = d_RS[nii] + (l*l - an*an + m + l);
      v = z2[(size_t)(row*32+b)*200 + o];
    }
    zlh[e]=v;
  }
  __syncthreads();
  const float* di2 = tbl + OFF_DI2;
  const float* wo  = tbl + OFF_WO;
  float b2v = b2[o];
  float acc0=0.f, acc1=0.f;
  for (int zz=0; zz<5; zz++){
    int z = w*5 + zz;
    // ---- G[m][nii] = sum_l di2[l][z][(m+4)*9+nii] * zlh[l][m][nii], m=0..4 ----
    if (lane < 45){
      int m=lane/9, nii=lane%9;
      float gx=0.f, gy=0.f;
      #pragma unroll
      for (int l=0;l<5;l++){
        float wv = di2[(l*10+z)*81 + (m+4)*9 + nii];
        float2 v = zlh[(l*5+m)*9+nii];
        gx += wv*v.x; gy += wv*v.y;
      }
      Gw[w][lane]=make_float2(gx,gy);
    }
    // ---- F[m][j2] = sum_n G[m][n] e^{i n a_j2}; F[0] real ----
    if (lane < 50){
      int m=lane/10, j2=lane%10;
      if (m==0){
        float f0 = Gw[w][4].x;
        #pragma unroll
        for (int n=1;n<=4;n++){
          int idx=(n*j2)%10;
          float2 g=Gw[w][4+n];
          f0 += 2.f*(c10s[idx]*g.x - s10s[idx]*g.y);
        }
        Fw[w][lane]=make_float2(f0, 0.f);
      } else {
        float fx=0.f, fy=0.f;
        #pragma unroll
        for (int nii=0;nii<9;nii++){
          int n=nii-4;
          int idx=((n*j2)%10+10)%10;
          float2 g=Gw[w][m*9+nii];
          fx += c10s[idx]*g.x - s10s[idx]*g.y;
          fy += s10s[idx]*g.x + c10s[idx]*g.y;
        }
        Fw[w][lane]=make_float2(fx,fy);
      }
    }
    // ---- r[j1][j2] = b2 + F0[j2] + 2*sum_{m=1..4} Re(e^{i m a_j1} F[m][j2]); pooled ----
    float wz = wo[z];
    {
      int j1=lane/10, j2=lane%10;     // pass0: e=lane<64
      float v = b2v + Fw[w][j2].x;
      #pragma unroll
      for (int m=1;m<=4;m++){
        int idx=(m*j1)%10;
        float2 f=Fw[w][m*10+j2];
        v += 2.f*(c10s[idx]*f.x - s10s[idx]*f.y);
      }
      acc0 += wz*fmaxf(v,0.f);
    }
    if (lane < 36){
      int e=lane+64, j1=e/10, j2=e%10; // pass1
      float v = b2v + Fw[w][j2].x;
      #pragma unroll
      for (int m=1;m<=4;m++){
        int idx=(m*j1)%10;
        float2 f=Fw[w][m*10+j2];
        v += 2.f*(c10s[idx]*f.x - s10s[idx]*f.y);
      }
      acc1 += wz*fmaxf(v,0.f);
    }
  }
  float a = acc0 + acc1;
  #pragma unroll
  for (int s=32;s>0;s>>=1) a += __shfl_down(a, s);
  if (lane==0) red2[w]=a;
  __syncthreads();
  if (t==0) fv[b*200+o]=red2[0]+red2[1];
}

// ---------------- K9: out[b][c] = bl[c] + sum_o W[c][o] fv[b][o]; one block per b ----------------
__global__ void k_out(const float* __restrict__ fv, const float* __restrict__ W,
                      const float* __restrict__ bl, float* __restrict__ out){
  int b = blockIdx.x, lane = threadIdx.x;
  float acc[10];
  #pragma unroll
  for (int c=0;c<10;c++) acc[c]=0.f;
  #pragma unroll
  for (int k=0;k<4;k++){
    int o = lane + 64*k;
    if (o < 200){
      float fvx = fv[b*200+o];
      #pragma unroll
      for (int c=0;c<10;c++) acc[c] += W[c*200+o]*fvx;
    }
  }
  #pragma unroll
  for (int c=0;c<10;c++){
    float a = acc[c];
    #pragma unroll
    for (int s=32;s>0;s>>=1) a += __shfl_down(a, s);
    if (lane==0) out[b*10+c] = a + bl[c];
  }
}

// ======================= host-side constant tables =======================
namespace {

double dfact_[40];
void init_fact(){ dfact_[0]=1.0; for (int i=1;i<40;i++) dfact_[i]=dfact_[i-1]*i; }

double wigd(int l, double beta, int m, int n){
  double cb=std::cos(beta*0.5), sb=std::sin(beta*0.5);
  double pref=std::sqrt(dfact_[l+m]*dfact_[l-m]*dfact_[l+n]*dfact_[l-n]);
  int s0=std::max(0,n-m), s1=std::min(l+n,l-m);
  double acc=0.0;
  for (int s=s0;s<=s1;s++){
    double den=dfact_[l+n-s]*dfact_[s]*dfact_[m-n+s]*dfact_[l-m-s];
    double sg=((m-n+s)&1)?-1.0:1.0;
    acc+=sg/den*std::pow(cb,(double)(2*l+n-m-2*s))*std::pow(sb,(double)(m-n+2*s));
  }
  return pref*acc;
}

void quadw(int b, double* betas, double* w){
  int n=2*b;
  for (int j=0;j<n;j++){
    betas[j]=M_PI*(2*j+1)/(4.0*b);
    double s=0.0;
    for (int k=1;k<2*b;k+=2) s+=std::sin(k*betas[j])/k;
    w[j]=2.0/b*std::sin(betas[j])*s;
  }
}

float* g_tbl_host = nullptr;

void build_tables(){
  init_fact();
  double bin[60], win[60], bl1[20], wl1[20], bo10[10], wo10[10];
  quadw(30,bin,win); quadw(10,bl1,wl1); quadw(5,bo10,wo10);
  float* T = g_tbl_host;
  memset(T, 0, TBL_N*sizeof(float));
  for (int l=0;l<10;l++) for (int z=0;z<60;z++) for (int mi=0;mi<19;mi++){
    int m=mi-9; if (m<-l||m>l) continue;
    T[OFF_D1W+(l*60+z)*19+mi]=(float)(win[z]*wigd(l,bin[z],m,0));
  }
  for (int l=0;l<10;l++) for (int z=0;z<20;z++) for (int mi=0;mi<19;mi++) for (int ni=0;ni<19;ni++){
    int m=mi-9, n=ni-9; if (m<-l||m>l||n<-l||n>l) continue;
    T[OFF_C1+(l*20+z)*361+mi*19+ni]=(float)((2*l+1)*wigd(l,bl1[z],m,n)*wigd(l,M_PI/2,n,0));
  }
  for (int l=0;l<5;l++) for (int z=0;z<20;z++) for (int mi=0;mi<9;mi++) for (int ki=0;ki<9;ki++){
    int m=mi-4, k=ki-4; if (m<-l||m>l||k<-l||k>l) continue;
    T[OFF_D2W+(l*20+z)*81+mi*9+ki]=(float)(wl1[z]*wigd(l,bl1[z],m,k));
  }
  for (int l=0;l<5;l++) for (int ni=0;ni<9;ni++) for (int ki=0;ki<9;ki++){
    int n=ni-4, k=ki-4; if (n<-l||n>l||k<-l||k>l) continue;
    T[OFF_DH2+l*81+ni*9+ki]=(float)wigd(l,M_PI/2,n,k);
  }
  for (int l=0;l<5;l++) for (int z=0;z<10;z++) for (int mi=0;mi<9;mi++) for (int ni=0;ni<9;ni++){
    int m=mi-4, n=ni-4; if (m<-l||m>l||n<-l||n>l) continue;
    T[OFF_DI2+(l*10+z)*81+mi*9+ni]=(float)((2*l+1)*wigd(l,bo10[z],m,n));
  }
  for (int z=0;z<10;z++) T[OFF_WO+z]=(float)wo10[z];
}

struct GInit {
  GInit(){
    if (hipHostMalloc((void**)&g_tbl_host, TBL_N*sizeof(float)) != hipSuccess || !g_tbl_host){
      g_tbl_host = (float*)malloc(TBL_N*sizeof(float));
    }
    build_tables();
  }
};
GInit g_init_;

} // namespace

extern "C" void kernel_launch(void* const* d_in, const int* in_sizes, int n_in,
                              void* d_out, int out_size, void* d_ws, size_t ws_size,
                              hipStream_t stream) {
  const float* x  = (const float*)d_in[0];
  const float* k1 = (const float*)d_in[1];
  const float* b1 = (const float*)d_in[2];
  const float* k2 = (const float*)d_in[3];
  const float* b2 = (const float*)d_in[4];
  const float* W  = (const float*)d_in[5];
  const float* bl = (const float*)d_in[6];
  float* out = (float*)d_out;

  size_t off = 0;
  auto carve = [&](size_t bytes)->void*{
    void* p = (char*)d_ws + off;
    off += (bytes + 255) & ~(size_t)255;
    return p;
  };
  float*  t_tbl = (float*) carve((size_t)TBL_N*4);
  float2* kf1   = (float2*)carve((size_t)19*100*8);
  float2* kf2   = (float2*)carve((size_t)9*100*200*8);
  float2* xf1   = (float2*)carve((size_t)19*32*60*8);
  float2* xh1   = (float2*)carve((size_t)10*19*32*8);
  float2* Qb    = (float2*)carve((size_t)32*20*361*8);
  float2* Pb    = (float2*)carve((size_t)32*20*200*8);
  float2* xf2   = (float2*)carve((size_t)3200*900*8);   // half-stored (M>=0)
  float2* xh2   = (float2*)carve((size_t)405*3200*8);
  float2* Am    = (float2*)carve((size_t)165*32*100*8);
  float2* z2    = (float2*)carve((size_t)165*32*200*8);
  float*  fv    = (float*) carve((size_t)6400*4);
  (void)ws_size; (void)in_sizes; (void)n_in; (void)out_size;

  hipMemcpyAsync(t_tbl, g_tbl_host, (size_t)TBL_N*4, hipMemcpyHostToDevice, stream);

  k_front<<<223, 256, 0, stream>>>(k1, k2, x, kf1, kf2, xf1);
  k_xhat1<<<24, 256, 0, stream>>>(t_tbl, xf1, xh1);
  k_Q    <<<903, 256, 0, stream>>>(t_tbl, xh1, Qb);
  k_P    <<<500, 256, 0, stream>>>(Qb, Pb);
  k_l1   <<<3200, 256, 0, stream>>>(Pb, kf1, b1, xf2);
  k_xhat2<<<800, 256, 0, stream>>>(t_tbl, xf2, xh2);
  k_Xp   <<<dim3(313, 9), 256, 0, stream>>>(t_tbl, xh2, Am);
  k_gemm <<<dim3(13, 4, 9), 256, 0, stream>>>(Am, kf2, z2);
  k_l2   <<<6400, 128, 0, stream>>>(t_tbl, z2, b2, fv);
  k_out  <<<32, 64, 0, stream>>>(fv, W, bl, out);
}

// Round 6
// 326.237 us; speedup vs baseline: 2.1134x; 2.1134x over previous
//
#include <hip/hip_runtime.h>
#include <cmath>
#include <cstring>
#include <cstdlib>
#include <algorithm>

// ---------------- problem constants ----------------
#define BATCH 32

static constexpr float SC1f = 0.03872983346207417f;   // 1/sqrt(2*30*1*10^4/30^2)
static constexpr float SC2f = 0.06324555320336759f;   // 1/sqrt(250)

// table layout (float offsets inside the table blob)
#define OFF_D1W 0
#define N_D1W (10*60*19)
#define OFF_C1  (OFF_D1W + N_D1W)      // [10][20][19][19]
#define N_C1  (10*20*19*19)
#define OFF_D2W (OFF_C1 + N_C1)        // [5][20][9][9]
#define N_D2W (5*20*81)
#define OFF_DH2 (OFF_D2W + N_D2W)      // [5][9][9]
#define N_DH2 (5*81)
#define OFF_DI2 (OFF_DH2 + N_DH2)      // [5][10][9][9]
#define N_DI2 (5*10*81)
#define OFF_WO  (OFF_DI2 + N_DI2)      // [10]
#define TBL_N   (OFF_WO + 10)

__constant__ int d_RNI[9] = {9,16,21,24,25,24,21,16,9};
__constant__ int d_RS [9] = {0,9,25,46,70,95,119,140,156};

__device__ __forceinline__ float2 cmulf(float2 a, float2 b){
  return make_float2(a.x*b.x - a.y*b.y, a.x*b.y + a.y*b.x);
}

// ---------------- K_front: kf1 (block 0) | kf2 (blocks 1..79) | xf1 (blocks 80..222) ----------------
__global__ void k_front(const float* __restrict__ k1, const float* __restrict__ k2,
                        const float* __restrict__ x,
                        float2* __restrict__ kf1, float2* __restrict__ kf2,
                        float2* __restrict__ xf1){
  __shared__ float c60[60], s60[60], c20[20], s20[20];
  int t = threadIdx.x;
  if (t < 60){ float a = 6.283185307179586f * t / 60.f; c60[t]=cosf(a); s60[t]=sinf(a); }
  if (t < 20){ float a = 6.283185307179586f * t / 20.f; c20[t]=cosf(a); s20[t]=sinf(a); }
  __syncthreads();
  int bid = blockIdx.x;
  if (bid == 0){
    int o = t;
    if (o >= 100) return;
    float kv[60];
    for (int j=0;j<60;j++) kv[j] = k1[o*60+j];
    for (int mi=0; mi<19; mi++){
      int m = mi-9; float ax=0.f, ay=0.f;
      for (int j=0;j<60;j++){
        int idx = ((m*j)%60+60)%60;
        ax += kv[j]*c60[idx]; ay -= kv[j]*s60[idx];
      }
      kf1[mi*100+o] = make_float2(ax*SC1f, ay*SC1f);
    }
  } else if (bid < 80){
    int gid = (bid-1)*256 + t;
    if (gid >= 20000) return;
    int i = gid/200, o = gid%200;
    float kv[20];
    for (int p=0;p<20;p++) kv[p] = k2[(i*200+o)*20+p];
    for (int mi=0; mi<9; mi++){
      int m = mi-4; float ax=0.f, ay=0.f;
      for (int p=0;p<20;p++){
        int idx = ((m*p)%20+20)%20;
        ax += kv[p]*c20[idx]; ay -= kv[p]*s20[idx];
      }
      kf2[(size_t)(mi*100+i)*200+o] = make_float2(ax*SC2f, ay*SC2f);
    }
  } else {
    int gid = (bid-80)*256 + t;
    if (gid >= 19*32*60) return;
    int z = gid%60, b = (gid/60)%32, mi = gid/1920;
    int m = mi-9;
    const float* xr = x + (b*60 + z)*60;
    float ax=0.f, ay=0.f;
    for (int j=0;j<60;j++){
      int idx = ((m*j)%60+60)%60;
      float xv = xr[j];
      ax += xv*c60[idx]; ay -= xv*s60[idx];
    }
    xf1[(mi*32+b)*60+z] = make_float2(ax, ay);
  }
}

// ---------------- K2b: xh1[l][mi][b] ----------------
__global__ void k_xhat1(const float* __restrict__ tbl, const float2* __restrict__ xf1,
                        float2* __restrict__ xh1){
  int gid = blockIdx.x*256 + threadIdx.x;
  if (gid >= 10*19*32) return;
  int b = gid%32, mi = (gid/32)%19, l = gid/608;
  const float* d1w = tbl + OFF_D1W;
  float ax=0.f, ay=0.f;
  for (int z=0;z<60;z++){
    float w = d1w[(l*60+z)*19+mi];
    float2 v = xf1[(mi*32+b)*60+z];
    ax += w*v.x; ay += w*v.y;
  }
  xh1[(l*19+mi)*32+b] = make_float2(ax, ay);
}

// ---------------- K3: Q[b][z][mi][ni] = sum_l C1[l][z][mi][ni] * xh1[l][mi][b] ----------------
__global__ void k_Q(const float* __restrict__ tbl, const float2* __restrict__ xh1,
                    float2* __restrict__ Q){
  int gid = blockIdx.x*256 + threadIdx.x;
  if (gid >= 32*20*361) return;
  int ni = gid%19, mi = (gid/19)%19, z = (gid/361)%20, b = gid/7220;
  const float* C1 = tbl + OFF_C1;
  float ax=0.f, ay=0.f;
  for (int l=0;l<10;l++){
    float c = C1[(l*20+z)*361 + mi*19+ni];
    float2 xv = xh1[(l*19+mi)*32+b];
    ax += c*xv.x; ay += c*xv.y;
  }
  Q[gid] = make_float2(ax, ay);
}

// ---------------- K3b: P[b][z][n][j1] = sum_{mi} e^{i(mi-9)a_{j1}} Q[b][z][mi][n+9], n=0..9 ----------------
__global__ void k_P(const float2* __restrict__ Q, float2* __restrict__ P){
  __shared__ float c20[20], s20[20];
  int t = threadIdx.x;
  if (t < 20){ float a = 6.283185307179586f * t / 20.f; c20[t]=cosf(a); s20[t]=sinf(a); }
  __syncthreads();
  int gid = blockIdx.x*256 + t;
  if (gid >= 128000) return;
  int j1 = gid%20, n = (gid/20)%10, z = (gid/200)%20, b = gid/4000;
  const float2* q = Q + (size_t)(b*20+z)*361 + (n+9);
  float px=0.f, py=0.f;
  for (int mi=0;mi<19;mi++){
    int idx = (((mi-9)*j1)%20+20)%20;
    float c=c20[idx], s=s20[idx];
    float2 v = q[mi*19];
    px += c*v.x - s*v.y;
    py += c*v.y + s*v.x;
  }
  P[gid] = make_float2(px, py);
}

// ---------------- K4: fused layer-1 synthesis + ReLU + layer-2 analysis ----------------
// Per block (b,o); wave w owns z = w*5+zz. V[n][j1] in registers (lane=j1 mod 20),
// twiddles via complex recurrence; r in per-wave LDS; A per-wave LDS; slab written
// half-stored (M>=0): xf2[(b*100+o)][z][45].
// launch_bounds(256,2): 128-VGPR cap, no spill (R3: 109us). (256,4)->64 VGPR and
// (256,3)->84 VGPR both spill to scratch: >1 GB HBM traffic, 4x slower (R2/R4).
__launch_bounds__(256,2)
__global__ void k_l1(const float2* __restrict__ P, const float2* __restrict__ kf1,
                     const float* __restrict__ b1, float2* __restrict__ xf2){
  int o = blockIdx.x % 100, b = blockIdx.x / 100;
  __shared__ float  rsb[4][400];   // [wave][j1][j2]
  __shared__ float2 Aw[4][100];    // [wave][j1][N 0..4]
  int t = threadIdx.x, w = t>>6, lane = t&63;
  int j1 = lane%20, jg = lane/20;  // jg==3 lanes idle in r phase
  const float a1 = 0.314159265358979f; // 2*pi/20

  // block-lifetime register constants
  float2 kc[10];
  #pragma unroll
  for (int n=0;n<10;n++){ float2 k = kf1[(n+9)*100+o]; kc[n]=make_float2(k.x,-k.y); }
  float b1v = b1[o];
  float2 w1p[4];
  #pragma unroll
  for (int k=0;k<4;k++){
    float a = a1 * (jg + 3*k);
    w1p[k] = make_float2(cosf(a), sinf(a));   // e^{+i a_{j2}}
  }
  float2 wN[2];
  #pragma unroll
  for (int pass=0;pass<2;pass++){
    int N = (lane + 64*pass)%5;
    float a = a1 * N;
    wN[pass] = make_float2(cosf(a), -sinf(a)); // e^{-i N a1}
  }
  int M = (lane<45)? lane/9 : 0;
  float2 wM = make_float2(cosf(a1*M), -sinf(a1*M)); // e^{-i M a1}

  for (int zz=0; zz<5; zz++){
    int z = w*5 + zz;
    // ---- V[n] = P[n][j1] * conj(kf1[n]) in registers ----
    float Vx[10], Vy[10];
    const float2* pz = P + (size_t)(b*20+z)*200;
    #pragma unroll
    for (int n=0;n<10;n++){
      float2 p = pz[n*20 + j1];
      Vx[n] = p.x*kc[n].x - p.y*kc[n].y;
      Vy[n] = p.x*kc[n].y + p.y*kc[n].x;
    }
    // ---- r[j1][j2] with j2/j2+10 parity pairing ----
    if (jg < 3){
      #pragma unroll
      for (int k=0;k<4;k++){
        int j2 = jg + 3*k;
        if (j2 < 10){
          float2 cur = w1p[k];
          float ae=0.f, ao=0.f;
          #pragma unroll
          for (int n=1;n<10;n++){
            float tr = Vx[n]*cur.x - Vy[n]*cur.y;
            if (n&1) ao += tr; else ae += tr;
            if (n<9) cur = cmulf(cur, w1p[k]);
          }
          float base = b1v + Vx[0];
          rsb[w][j1*20+j2]    = fmaxf(base + 2.f*(ae+ao), 0.f);
          rsb[w][j1*20+j2+10] = fmaxf(base + 2.f*(ae-ao), 0.f);
        }
      }
    }
    // wave-private LDS; a wave's DS ops complete in order -> no block barrier needed
    // ---- A[j1][N] = sum_j2 r[j1][j2] e^{-i N a_{j2}}, N=0..4 ----
    #pragma unroll
    for (int pass=0; pass<2; pass++){
      int e = lane + pass*64;
      if (e < 100){
        int aj1 = e/5;
        const float4* rrow = (const float4*)&rsb[w][aj1*20];
        float2 wNp = wN[pass];
        float2 cur = make_float2(1.f, 0.f);
        float ax=0.f, ay=0.f;
        #pragma unroll
        for (int q4=0;q4<5;q4++){
          float4 f = rrow[q4];
          ax += f.x*cur.x; ay += f.x*cur.y; cur = cmulf(cur, wNp);
          ax += f.y*cur.x; ay += f.y*cur.y; cur = cmulf(cur, wNp);
          ax += f.z*cur.x; ay += f.z*cur.y; cur = cmulf(cur, wNp);
          ax += f.w*cur.x; ay += f.w*cur.y; cur = cmulf(cur, wNp);
        }
        Aw[w][e] = make_float2(ax, ay);
      }
    }
    // ---- slab[M][Ni] = sum_j1 e^{-i M a_{j1}} A[j1][N], M=0..4, Ni=0..8 ----
    if (lane < 45){
      int Ni = lane%9, N = Ni-4;
      int sidx = (N>=0)? N : -N;
      float ysgn = (N>=0)? 1.f : -1.f;
      float2 cur = make_float2(1.f,0.f);
      float ox=0.f, oy=0.f;
      #pragma unroll
      for (int q=0;q<20;q++){
        float2 A = Aw[w][q*5+sidx];
        float Ay2 = ysgn*A.y;
        ox += cur.x*A.x - cur.y*Ay2;
        oy += cur.x*Ay2 + cur.y*A.x;
        cur = cmulf(cur, wM);
      }
      xf2[((size_t)(b*100+o)*20 + z)*45 + lane] = make_float2(ox, oy);
    }
  }
}

// ---------------- K5: xh2 from half-stored xf2 (conjugate mirror on read) ----------------
__launch_bounds__(256)
__global__ void k_xhat2(const float* __restrict__ tbl, const float2* __restrict__ xf2,
                        float2* __restrict__ xh2){
  __shared__ float2 xs[4][900]; // [ii][z][45]
  int b = blockIdx.x/25, ic = blockIdx.x%25;
  int t = threadIdx.x;
  const float2* src = xf2 + (size_t)(b*100 + ic*4)*900;
  for (int e=t;e<3600;e+=256) xs[e/900][e%900]=src[e];
  __syncthreads();
  const float* d2w = tbl + OFF_D2W;
  for (int e=t;e<1620;e+=256){
    int lmk=e>>2, ii=e&3;
    int l=lmk/81, mk=lmk%81;
    int mi=mk/9, ki=mk%9;
    int sidx; float sgn;
    if (mi>=4){ sidx=(mi-4)*9+ki; sgn=1.f; }
    else      { sidx=(4-mi)*9+(8-ki); sgn=-1.f; }
    float ax=0.f, ay=0.f;
    for (int z=0;z<20;z++){
      float wv=d2w[(l*20+z)*81+mk];
      float2 v=xs[ii][z*45+sidx];
      ax += wv*v.x; ay += wv*sgn*v.y;
    }
    xh2[(size_t)lmk*3200 + b*100 + ic*4 + ii]=make_float2(ax,ay);
  }
}

// ---------------- K6: A rows for GEMM ----------------
__global__ void k_Xp(const float* __restrict__ tbl, const float2* __restrict__ xh2,
                     float2* __restrict__ Am){
  int ni = blockIdx.y;
  int R = d_RNI[ni];
  int gid = blockIdx.x*256 + threadIdx.x;
  if (gid >= R*3200) return;
  int r = gid/3200, rem = gid%3200, b = rem/100, i = rem%100;
  int a = ni-4; if (a<0) a=-a;
  int l=a, rr=r;
  while (rr >= 2*l+1){ rr -= 2*l+1; l++; }
  int m = rr - l;
  const float* dh2 = tbl + OFF_DH2;
  float ax=0.f, ay=0.f;
  for (int ki=0; ki<2*l+1; ki++){
    int k = ki - l;
    float w = dh2[l*81 + ni*9 + (k+4)];
    float2 v = xh2[(size_t)(l*81 + (m+4)*9 + (k+4))*3200 + b*100 + i];
    ax += w*v.x; ay += w*v.y;
  }
  Am[(size_t)((d_RS[ni]+r)*32 + b)*100 + i] = make_float2(ax,ay);
}

// ---------------- K7: complex GEMM  z2[row][o] = sum_i Am[row][i] * conj(kf2[ni][i][o]) ----------------
__launch_bounds__(256)
__global__ void k_gemm(const float2* __restrict__ Am, const float2* __restrict__ kf2,
                       float2* __restrict__ z2){
  int ni = blockIdx.z;
  int rows = d_RNI[ni]*32;
  int r0 = blockIdx.x*64;
  if (r0 >= rows) return;
  int c0 = blockIdx.y*64;
  const float2* Ab = Am + (size_t)d_RS[ni]*32*100;
  const float2* Bb = kf2 + (size_t)ni*20000;
  float2* Cb = z2 + (size_t)d_RS[ni]*32*200;
  __shared__ float2 Asx[20*64];
  __shared__ float2 Bsx[20*64];
  int t = threadIdx.x;
  int tx = t%16, ty = t/16;
  float2 acc[4][4];
  for (int i2=0;i2<4;i2++) for (int j2=0;j2<4;j2++) acc[i2][j2]=make_float2(0.f,0.f);
  for (int k0=0;k0<100;k0+=20){
    for (int e=t;e<1280;e+=256){
      int m=e/20, k=e%20;
      float2 v=make_float2(0.f,0.f);
      if (r0+m<rows) v=Ab[(size_t)(r0+m)*100 + k0+k];
      Asx[k*64+m]=v;
    }
    for (int e=t;e<1280;e+=256){
      int k=e/64, n=e%64;
      float2 v=make_float2(0.f,0.f);
      if (c0+n<200){ v=Bb[(size_t)(k0+k)*200 + c0+n]; v.y=-v.y; }
      Bsx[k*64+n]=v;
    }
    __syncthreads();
    for (int k=0;k<20;k++){
      float2 av[4], bv[4];
      for (int i2=0;i2<4;i2++) av[i2]=Asx[k*64+ty*4+i2];
      for (int j2=0;j2<4;j2++) bv[j2]=Bsx[k*64+tx*4+j2];
      for (int i2=0;i2<4;i2++) for (int j2=0;j2<4;j2++){
        acc[i2][j2].x += av[i2].x*bv[j2].x - av[i2].y*bv[j2].y;
        acc[i2][j2].y += av[i2].x*bv[j2].y + av[i2].y*bv[j2].x;
      }
    }
    __syncthreads();
  }
  for (int i2=0;i2<4;i2++) for (int j2=0;j2<4;j2++){
    int row=r0+ty*4+i2, col=c0+tx*4+j2;
    if (row<rows && col<200) Cb[(size_t)row*200+col]=acc[i2][j2];
  }
}

// ---------------- K8: fused layer-2 synthesis + ReLU + quadrature pooling ----------------
// Hermitian-halved (G[-m,-n]=conj(G[m,n]), F[0] real); 2 waves, each owns 5 z,
// wave-private LDS scratch -> single block barrier.
__launch_bounds__(128)
__global__ void k_l2(const float* __restrict__ tbl, const float2* __restrict__ z2,
                     const float* __restrict__ b2, float* __restrict__ fv){
  int o = blockIdx.x % 200, b = blockIdx.x / 200;
  __shared__ float2 zlh[225];      // [l][m 0..4][nii] (m>=0 half)
  __shared__ float  c10s[10], s10s[10];
  __shared__ float2 Gw[2][45];     // [wave][m*9+nii]
  __shared__ float2 Fw[2][50];     // [wave][m*10+j2]
  __shared__ float  red2[2];
  int t = threadIdx.x, w = t>>6, lane = t&63;
  if (t < 10){ float a = 0.6283185307179586f * t; c10s[t]=cosf(a); s10s[t]=sinf(a); }
  for (int e=t;e<225;e+=128){
    int l=e/45, rm=e%45, m=rm/9, nii=rm%9;
    int n=nii-4, an = n<0?-n:n;
    float2 v=make_float2(0.f,0.f);
    if (l >= m && l >= an){
      int row = d_RS[nii] + (l*l - an*an + m + l);
      v = z2[(size_t)(row*32+b)*200 + o];
    }
    zlh[e]=v;
  }
  __syncthreads();
  const float* di2 = tbl + OFF_DI2;
  const float* wo  = tbl + OFF_WO;
  float b2v = b2[o];
  float acc0=0.f, acc1=0.f;
  for (int zz=0; zz<5; zz++){
    int z = w*5 + zz;
    // ---- G[m][nii] = sum_l di2[l][z][(m+4)*9+nii] * zlh[l][m][nii], m=0..4 ----
    if (lane < 45){
      int m=lane/9, nii=lane%9;
      float gx=0.f, gy=0.f;
      #pragma unroll
      for (int l=0;l<5;l++){
        float wv = di2[(l*10+z)*81 + (m+4)*9 + nii];
        float2 v = zlh[(l*5+m)*9+nii];
        gx += wv*v.x; gy += wv*v.y;
      }
      Gw[w][lane]=make_float2(gx,gy);
    }
    // ---- F[m][j2] = sum_n G[m][n] e^{i n a_j2}; F[0] real ----
    if (lane < 50){
      int m=lane/10, j2=lane%10;
      if (m==0){
        float f0 = Gw[w][4].x;
        #pragma unroll
        for (int n=1;n<=4;n++){
          int idx=(n*j2)%10;
          float2 g=Gw[w][4+n];
          f0 += 2.f*(c10s[idx]*g.x - s10s[idx]*g.y);
        }
        Fw[w][lane]=make_float2(f0, 0.f);
      } else {
        float fx=0.f, fy=0.f;
        #pragma unroll
        for (int nii=0;nii<9;nii++){
          int n=nii-4;
          int idx=((n*j2)%10+10)%10;
          float2 g=Gw[w][m*9+nii];
          fx += c10s[idx]*g.x - s10s[idx]*g.y;
          fy += s10s[idx]*g.x + c10s[idx]*g.y;
        }
        Fw[w][lane]=make_float2(fx,fy);
      }
    }
    // ---- r[j1][j2] = b2 + F0[j2] + 2*sum_{m=1..4} Re(e^{i m a_j1} F[m][j2]); pooled ----
    float wz = wo[z];
    {
      int j1=lane/10, j2=lane%10;     // pass0: e=lane<64
      float v = b2v + Fw[w][j2].x;
      #pragma unroll
      for (int m=1;m<=4;m++){
        int idx=(m*j1)%10;
        float2 f=Fw[w][m*10+j2];
        v += 2.f*(c10s[idx]*f.x - s10s[idx]*f.y);
      }
      acc0 += wz*fmaxf(v,0.f);
    }
    if (lane < 36){
      int e=lane+64, j1=e/10, j2=e%10; // pass1
      float v = b2v + Fw[w][j2].x;
      #pragma unroll
      for (int m=1;m<=4;m++){
        int idx=(m*j1)%10;
        float2 f=Fw[w][m*10+j2];
        v += 2.f*(c10s[idx]*f.x - s10s[idx]*f.y);
      }
      acc1 += wz*fmaxf(v,0.f);
    }
  }
  float a = acc0 + acc1;
  #pragma unroll
  for (int s=32;s>0;s>>=1) a += __shfl_down(a, s);
  if (lane==0) red2[w]=a;
  __syncthreads();
  if (t==0) fv[b*200+o]=red2[0]+red2[1];
}

// ---------------- K9: out[b][c] = bl[c] + sum_o W[c][o] fv[b][o]; one block per b ----------------
__global__ void k_out(const float* __restrict__ fv, const float* __restrict__ W,
                      const float* __restrict__ bl, float* __restrict__ out){
  int b = blockIdx.x, lane = threadIdx.x;
  float acc[10];
  #pragma unroll
  for (int c=0;c<10;c++) acc[c]=0.f;
  #pragma unroll
  for (int k=0;k<4;k++){
    int o = lane + 64*k;
    if (o < 200){
      float fvx = fv[b*200+o];
      #pragma unroll
      for (int c=0;c<10;c++) acc[c] += W[c*200+o]*fvx;
    }
  }
  #pragma unroll
  for (int c=0;c<10;c++){
    float a = acc[c];
    #pragma unroll
    for (int s=32;s>0;s>>=1) a += __shfl_down(a, s);
    if (lane==0) out[b*10+c] = a + bl[c];
  }
}

// ======================= host-side constant tables =======================
namespace {

double dfact_[40];
void init_fact(){ dfact_[0]=1.0; for (int i=1;i<40;i++) dfact_[i]=dfact_[i-1]*i; }

double wigd(int l, double beta, int m, int n){
  double cb=std::cos(beta*0.5), sb=std::sin(beta*0.5);
  double pref=std::sqrt(dfact_[l+m]*dfact_[l-m]*dfact_[l+n]*dfact_[l-n]);
  int s0=std::max(0,n-m), s1=std::min(l+n,l-m);
  double acc=0.0;
  for (int s=s0;s<=s1;s++){
    double den=dfact_[l+n-s]*dfact_[s]*dfact_[m-n+s]*dfact_[l-m-s];
    double sg=((m-n+s)&1)?-1.0:1.0;
    acc+=sg/den*std::pow(cb,(double)(2*l+n-m-2*s))*std::pow(sb,(double)(m-n+2*s));
  }
  return pref*acc;
}

void quadw(int b, double* betas, double* w){
  int n=2*b;
  for (int j=0;j<n;j++){
    betas[j]=M_PI*(2*j+1)/(4.0*b);
    double s=0.0;
    for (int k=1;k<2*b;k+=2) s+=std::sin(k*betas[j])/k;
    w[j]=2.0/b*std::sin(betas[j])*s;
  }
}

float* g_tbl_host = nullptr;

void build_tables(){
  init_fact();
  double bin[60], win[60], bl1[20], wl1[20], bo10[10], wo10[10];
  quadw(30,bin,win); quadw(10,bl1,wl1); quadw(5,bo10,wo10);
  float* T = g_tbl_host;
  memset(T, 0, TBL_N*sizeof(float));
  for (int l=0;l<10;l++) for (int z=0;z<60;z++) for (int mi=0;mi<19;mi++){
    int m=mi-9; if (m<-l||m>l) continue;
    T[OFF_D1W+(l*60+z)*19+mi]=(float)(win[z]*wigd(l,bin[z],m,0));
  }
  for (int l=0;l<10;l++) for (int z=0;z<20;z++) for (int mi=0;mi<19;mi++) for (int ni=0;ni<19;ni++){
    int m=mi-9, n=ni-9; if (m<-l||m>l||n<-l||n>l) continue;
    T[OFF_C1+(l*20+z)*361+mi*19+ni]=(float)((2*l+1)*wigd(l,bl1[z],m,n)*wigd(l,M_PI/2,n,0));
  }
  for (int l=0;l<5;l++) for (int z=0;z<20;z++) for (int mi=0;mi<9;mi++) for (int ki=0;ki<9;ki++){
    int m=mi-4, k=ki-4; if (m<-l||m>l||k<-l||k>l) continue;
    T[OFF_D2W+(l*20+z)*81+mi*9+ki]=(float)(wl1[z]*wigd(l,bl1[z],m,k));
  }
  for (int l=0;l<5;l++) for (int ni=0;ni<9;ni++) for (int ki=0;ki<9;ki++){
    int n=ni-4, k=ki-4; if (n<-l||n>l||k<-l||k>l) continue;
    T[OFF_DH2+l*81+ni*9+ki]=(float)wigd(l,M_PI/2,n,k);
  }
  for (int l=0;l<5;l++) for (int z=0;z<10;z++) for (int mi=0;mi<9;mi++) for (int ni=0;ni<9;ni++){
    int m=mi-4, n=ni-4; if (m<-l||m>l||n<-l||n>l) continue;
    T[OFF_DI2+(l*10+z)*81+mi*9+ni]=(float)((2*l+1)*wigd(l,bo10[z],m,n));
  }
  for (int z=0;z<10;z++) T[OFF_WO+z]=(float)wo10[z];
}

struct GInit {
  GInit(){
    if (hipHostMalloc((void**)&g_tbl_host, TBL_N*sizeof(float)) != hipSuccess || !g_tbl_host){
      g_tbl_host = (float*)malloc(TBL_N*sizeof(float));
    }
    build_tables();
  }
};
GInit g_init_;

} // namespace

extern "C" void kernel_launch(void* const* d_in, const int* in_sizes, int n_in,
                              void* d_out, int out_size, void* d_ws, size_t ws_size,
                              hipStream_t stream) {
  const float* x  = (const float*)d_in[0];
  const float* k1 = (const float*)d_in[1];
  const float* b1 = (const float*)d_in[2];
  const float* k2 = (const float*)d_in[3];
  const float* b2 = (const float*)d_in[4];
  const float* W  = (const float*)d_in[5];
  const float* bl = (const float*)d_in[6];
  float* out = (float*)d_out;

  size_t off = 0;
  auto carve = [&](size_t bytes)->void*{
    void* p = (char*)d_ws + off;
    off += (bytes + 255) & ~(size_t)255;
    return p;
  };
  float*  t_tbl = (float*) carve((size_t)TBL_N*4);
  float2* kf1   = (float2*)carve((size_t)19*100*8);
  float2* kf2   = (float2*)carve((size_t)9*100*200*8);
  float2* xf1   = (float2*)carve((size_t)19*32*60*8);
  float2* xh1   = (float2*)carve((size_t)10*19*32*8);
  float2* Qb    = (float2*)carve((size_t)32*20*361*8);
  float2* Pb    = (float2*)carve((size_t)32*20*200*8);
  float2* xf2   = (float2*)carve((size_t)3200*900*8);   // half-stored (M>=0)
  float2* xh2   = (float2*)carve((size_t)405*3200*8);
  float2* Am    = (float2*)carve((size_t)165*32*100*8);
  float2* z2    = (float2*)carve((size_t)165*32*200*8);
  float*  fv    = (float*) carve((size_t)6400*4);
  (void)ws_size; (void)in_sizes; (void)n_in; (void)out_size;

  hipMemcpyAsync(t_tbl, g_tbl_host, (size_t)TBL_N*4, hipMemcpyHostToDevice, stream);

  k_front<<<223, 256, 0, stream>>>(k1, k2, x, kf1, kf2, xf1);
  k_xhat1<<<24, 256, 0, stream>>>(t_tbl, xf1, xh1);
  k_Q    <<<903, 256, 0, stream>>>(t_tbl, xh1, Qb);
  k_P    <<<500, 256, 0, stream>>>(Qb, Pb);
  k_l1   <<<3200, 256, 0, stream>>>(Pb, kf1, b1, xf2);
  k_xhat2<<<800, 256, 0, stream>>>(t_tbl, xf2, xh2);
  k_Xp   <<<dim3(313, 9), 256, 0, stream>>>(t_tbl, xh2, Am);
  k_gemm <<<dim3(13, 4, 9), 256, 0, stream>>>(Am, kf2, z2);
  k_l2   <<<6400, 128, 0, stream>>>(t_tbl, z2, b2, fv);
  k_out  <<<32, 64, 0, stream>>>(fv, W, bl, out);
}